// Round 1
// baseline (312.684 us; speedup 1.0000x reference)
//
#include <hip/hip_runtime.h>
#include <cstdint>
#include <cstddef>

#define N_INST 131072
#define D_EMB  512
#define ATT    128
#define NBAGS  256
#define TILE_I 64

// ---------------- workspace layout (floats) ----------------
// [0] Z1   (sum exp(att1) over all instances)
// [1] Z2   (sum exp(att2) over bags)
// [16..528)      v[512]      = W_c @ w_out  (folded classifier)
// [1024..1280)   e2[256]     = exp(att2) per bag
// [2048..2048+131072) raw[256][512] = unnormalized (then normalized) bag embeddings

// ============ K1: fused instance attention + weighted segment sum ============
// Per block: 64 instances. GEMM phase computes a1-pre [64x128] via LDS tiles,
// epilogue reduces to score s_i = exp(sigmoid(sum_j tanh(.)w_o1[j] + b_o1)),
// then segmented weighted accumulate of s_i * emb[i][:] into raw[bag][:].
__global__ __launch_bounds__(256) void k_att1(
    const float* __restrict__ emb, const int* __restrict__ lab,
    const float* __restrict__ Wa1, const float* __restrict__ ba1,
    const float* __restrict__ wo1, const float* __restrict__ bo1,
    float* __restrict__ raw, float* __restrict__ Z1)
{
    __shared__ float AsT[32][TILE_I];   // [k][i]  (transposed -> b128 reads on i)
    __shared__ float Bs[32][ATT];       // [k][j]
    __shared__ float att[TILE_I];
    __shared__ float sval[TILE_I];
    __shared__ int   labs[TILE_I];

    const int t  = threadIdx.x;
    const int i0 = blockIdx.x * TILE_I;
    const int tx = t & 15;              // hidden quad: j in {4tx..4tx+3} u {64+4tx..}
    const int ty = t >> 4;              // instance quad: i in {4ty..4ty+3}

    if (t < TILE_I) labs[t] = lab[i0 + t];

    float acc[4][8];
    #pragma unroll
    for (int a = 0; a < 4; ++a)
        #pragma unroll
        for (int b = 0; b < 8; ++b) acc[a][b] = 0.f;

    for (int k0 = 0; k0 < D_EMB; k0 += 32) {
        // stage A tile (64x32) transposed: 512 float4, 2 per thread
        #pragma unroll
        for (int r = 0; r < 2; ++r) {
            int idx = t + r * 256;
            int row = idx >> 3;           // 8 float4 per row
            int col = (idx & 7) * 4;
            float4 v = *reinterpret_cast<const float4*>(
                &emb[(size_t)(i0 + row) * D_EMB + k0 + col]);
            AsT[col + 0][row] = v.x;
            AsT[col + 1][row] = v.y;
            AsT[col + 2][row] = v.z;
            AsT[col + 3][row] = v.w;
        }
        // stage B tile (32x128): 1024 float4, 4 per thread
        #pragma unroll
        for (int r = 0; r < 4; ++r) {
            int idx = t + r * 256;
            int row = idx >> 5;           // 32 float4 per row
            int col = (idx & 31) * 4;
            *reinterpret_cast<float4*>(&Bs[row][col]) =
                *reinterpret_cast<const float4*>(&Wa1[(size_t)(k0 + row) * ATT + col]);
        }
        __syncthreads();
        #pragma unroll 8
        for (int kk = 0; kk < 32; ++kk) {
            float4 av = *reinterpret_cast<const float4*>(&AsT[kk][ty * 4]);
            float4 b0 = *reinterpret_cast<const float4*>(&Bs[kk][tx * 4]);
            float4 b1 = *reinterpret_cast<const float4*>(&Bs[kk][64 + tx * 4]);
            const float aa[4] = {av.x, av.y, av.z, av.w};
            const float bb[8] = {b0.x, b0.y, b0.z, b0.w, b1.x, b1.y, b1.z, b1.w};
            #pragma unroll
            for (int ii = 0; ii < 4; ++ii)
                #pragma unroll
                for (int jj = 0; jj < 8; ++jj)
                    acc[ii][jj] = fmaf(aa[ii], bb[jj], acc[ii][jj]);
        }
        __syncthreads();
    }

    // epilogue: att_pre[i] = sum_j tanh(acc + ba1[j]) * wo1[j]
    float part[4];
    #pragma unroll
    for (int ii = 0; ii < 4; ++ii) {
        float p = 0.f;
        #pragma unroll
        for (int jj = 0; jj < 8; ++jj) {
            int j = (jj < 4) ? (tx * 4 + jj) : (64 + tx * 4 + (jj - 4));
            p += tanhf(acc[ii][jj] + ba1[j]) * wo1[j];
        }
        part[ii] = p;
    }
    #pragma unroll
    for (int m = 1; m < 16; m <<= 1) {
        #pragma unroll
        for (int ii = 0; ii < 4; ++ii) part[ii] += __shfl_xor(part[ii], m);
    }
    if (tx == 0) {
        #pragma unroll
        for (int ii = 0; ii < 4; ++ii) att[ty * 4 + ii] = part[ii];
    }
    __syncthreads();
    if (t < TILE_I) {
        float a  = att[t] + bo1[0];
        float sg = 1.f / (1.f + __expf(-a));   // sigmoid in (0,1): exp needs no max-sub
        sval[t]  = __expf(sg);
    }
    __syncthreads();
    if (t < TILE_I) {          // threads 0..63 == wave 0
        float z = sval[t];
        #pragma unroll
        for (int m = 1; m < 64; m <<= 1) z += __shfl_xor(z, m);
        if (t == 0) atomicAdd(Z1, z);
    }

    // segmented weighted accumulate: thread t owns dims t and t+256.
    // Labels are sorted -> uniform branch, ~1 flush per block.
    int cur = labs[0];
    float a0 = 0.f, a1 = 0.f;
    for (int ii = 0; ii < TILE_I; ++ii) {
        int b = labs[ii];
        if (b != cur) {
            atomicAdd(&raw[cur * D_EMB + t], a0);
            atomicAdd(&raw[cur * D_EMB + 256 + t], a1);
            a0 = 0.f; a1 = 0.f; cur = b;
        }
        float s = sval[ii];
        const float* row = emb + (size_t)(i0 + ii) * D_EMB;   // L2-hot (just staged)
        a0 = fmaf(s, row[t], a0);
        a1 = fmaf(s, row[t + 256], a1);
    }
    atomicAdd(&raw[cur * D_EMB + t], a0);
    atomicAdd(&raw[cur * D_EMB + 256 + t], a1);
}

// ============ K2: normalize bag embeddings + bag-level attention ============
__global__ __launch_bounds__(128) void k_att2(
    const float* __restrict__ Wa2, const float* __restrict__ ba2,
    const float* __restrict__ wo2, const float* __restrict__ bo2,
    float* __restrict__ raw, const float* __restrict__ Z1,
    float* __restrict__ e2, float* __restrict__ Z2)
{
    __shared__ float sec[D_EMB];
    __shared__ float hh[2];
    const int b = blockIdx.x;
    const int t = threadIdx.x;
    const float zinv = 1.f / Z1[0];
    for (int d = t; d < D_EMB; d += 128) {
        float v = raw[b * D_EMB + d] * zinv;
        raw[b * D_EMB + d] = v;            // normalized in place
        sec[d] = v;
    }
    __syncthreads();
    float dot = 0.f;
    #pragma unroll 8
    for (int d = 0; d < D_EMB; ++d) dot = fmaf(sec[d], Wa2[d * ATT + t], dot);
    float h = tanhf(dot + ba2[t]) * wo2[t];
    #pragma unroll
    for (int m = 1; m < 64; m <<= 1) h += __shfl_xor(h, m);
    if ((t & 63) == 0) hh[t >> 6] = h;
    __syncthreads();
    if (t == 0) {
        float a  = hh[0] + hh[1] + bo2[0];
        float sg = 1.f / (1.f + __expf(-a));
        float e  = __expf(sg);
        e2[b] = e;
        atomicAdd(Z2, e);
    }
}

// ============ Kv: v = W_c @ w_out (data-independent classifier fold) ============
__global__ __launch_bounds__(256) void k_v(
    const float* __restrict__ Wc, const float* __restrict__ wout,
    float* __restrict__ v)
{
    const int t   = threadIdx.x;
    const int row = blockIdx.x * 8 + (t >> 5);
    const int l   = t & 31;
    float s = 0.f;
    #pragma unroll 4
    for (int c = l; c < 512; c += 32) s = fmaf(Wc[(size_t)row * 512 + c], wout[c], s);
    #pragma unroll
    for (int m = 1; m < 32; m <<= 1) s += __shfl_xor(s, m);
    if (l == 0) v[row] = s;
}

// ============ K4: bag softmax-pool + folded classifier -> pred ============
__global__ __launch_bounds__(256) void k_final(
    const float* __restrict__ raw, const float* __restrict__ e2,
    const float* __restrict__ Z2, const float* __restrict__ v,
    const float* __restrict__ bc, const float* __restrict__ wout,
    const float* __restrict__ bout, float* __restrict__ out)
{
    __shared__ float outer[D_EMB];
    __shared__ float pp[4];
    const int t = threadIdx.x;
    float o0 = 0.f, o1 = 0.f;
    for (int b = 0; b < NBAGS; ++b) {
        float w = e2[b];
        o0 = fmaf(w, raw[b * D_EMB + t], o0);
        o1 = fmaf(w, raw[b * D_EMB + 256 + t], o1);
    }
    const float z2inv = 1.f / Z2[0];
    outer[t]       = o0 * z2inv;
    outer[t + 256] = o1 * z2inv;
    __syncthreads();
    // pred = sigmoid( outer.v + bc.wout + bout )
    float p = outer[t] * v[t] + outer[t + 256] * v[t + 256]
            + bc[t] * wout[t] + bc[t + 256] * wout[t + 256];
    #pragma unroll
    for (int m = 1; m < 64; m <<= 1) p += __shfl_xor(p, m);
    if ((t & 63) == 0) pp[t >> 6] = p;
    __syncthreads();
    if (t == 0) {
        float s = pp[0] + pp[1] + pp[2] + pp[3] + bout[0];
        out[0] = 1.f / (1.f + __expf(-s));
    }
}

extern "C" void kernel_launch(void* const* d_in, const int* in_sizes, int n_in,
                              void* d_out, int out_size, void* d_ws, size_t ws_size,
                              hipStream_t stream)
{
    const float* emb  = (const float*)d_in[0];
    const int*   lab  = (const int*)d_in[1];
    const float* Wa1  = (const float*)d_in[2];
    const float* ba1  = (const float*)d_in[3];
    const float* wo1  = (const float*)d_in[4];
    const float* bo1  = (const float*)d_in[5];
    const float* Wa2  = (const float*)d_in[6];
    const float* ba2  = (const float*)d_in[7];
    const float* wo2  = (const float*)d_in[8];
    const float* bo2  = (const float*)d_in[9];
    const float* Wc   = (const float*)d_in[10];
    const float* bc   = (const float*)d_in[11];
    const float* wout = (const float*)d_in[12];
    const float* bout = (const float*)d_in[13];

    float* ws  = (float*)d_ws;
    float* Z1  = ws + 0;
    float* Z2  = ws + 1;
    float* v   = ws + 16;
    float* e2  = ws + 1024;
    float* raw = ws + 2048;

    // zero accumulators (Z1, Z2, raw) each call — harness does not re-poison
    hipMemsetAsync(d_ws, 0, (size_t)(2048 + NBAGS * D_EMB) * sizeof(float), stream);

    hipLaunchKernelGGL(k_v,    dim3(64),              dim3(256), 0, stream, Wc, wout, v);
    hipLaunchKernelGGL(k_att1, dim3(N_INST / TILE_I), dim3(256), 0, stream,
                       emb, lab, Wa1, ba1, wo1, bo1, raw, Z1);
    hipLaunchKernelGGL(k_att2, dim3(NBAGS),           dim3(128), 0, stream,
                       Wa2, ba2, wo2, bo2, raw, Z1, e2, Z2);
    hipLaunchKernelGGL(k_final, dim3(1),              dim3(256), 0, stream,
                       raw, e2, Z2, v, bc, wout, bout, (float*)d_out);
}

// Round 2
// 197.119 us; speedup vs baseline: 1.5863x; 1.5863x over previous
//
#include <hip/hip_runtime.h>
#include <cstdint>
#include <cstddef>

#define N_INST 131072
#define D_EMB  512
#define ATT    128
#define NBAGS  256
#define TILE_I 64
#define KC     64
#define LDA    72   // padded LDS row stride in bf16 elems (144 B -> conflict-free b128)

typedef __attribute__((ext_vector_type(8))) short  bf16x8;
typedef __attribute__((ext_vector_type(4))) float  f32x4;
typedef __attribute__((ext_vector_type(4))) unsigned short u16x4;

// ---------------- workspace layout (floats) ----------------
// [0] Z1, [1] Z2
// [16..528)      v[512]       = W_c @ w_out (folded classifier)
// [1024..1280)   e2[256]      = exp(att2) per bag
// [1536..2048)   outer[512]   = unnormalized softmax-pooled bag embedding
// [2048..133120) raw[256][512]
// [133120..165888) Wt bf16 [128][512]  (W_a1 transposed, n-major)

__device__ inline unsigned short f2b(float f) {
    unsigned u = __builtin_bit_cast(unsigned, f);
    u += 0x7FFFu + ((u >> 16) & 1u);          // RNE
    return (unsigned short)(u >> 16);
}

// ============ prep: Wt[n][k] = bf16(W_a1[k][n]) ============
__global__ __launch_bounds__(256) void k_prep_wt(
    const float* __restrict__ Wa1, unsigned short* __restrict__ Wt)
{
    const int n = blockIdx.x;
    for (int k = threadIdx.x; k < D_EMB; k += 256)
        Wt[(size_t)n * D_EMB + k] = f2b(Wa1[(size_t)k * ATT + n]);
}

// ============ K1: MFMA instance attention + weighted segment sum ============
__global__ __launch_bounds__(256) void k_att1(
    const float* __restrict__ emb, const int* __restrict__ lab,
    const unsigned short* __restrict__ Wt, const float* __restrict__ ba1,
    const float* __restrict__ wo1, const float* __restrict__ bo1,
    float* __restrict__ raw, float* __restrict__ Z1)
{
    __shared__ unsigned short Ash[TILE_I * LDA];  // [row i][k], stride LDA
    __shared__ unsigned short Bsh[ATT * LDA];     // [col n][k], stride LDA
    __shared__ float att[TILE_I];
    __shared__ float sval[TILE_I];
    __shared__ int   labs[TILE_I];

    const int t  = threadIdx.x;
    const int w  = t >> 6;        // wave id: owns instance rows 16w..16w+15
    const int l  = t & 63;
    const int l4 = l & 15;
    const int h4 = l >> 4;        // 0..3
    const size_t i0 = (size_t)blockIdx.x * TILE_I;

    if (t < TILE_I) labs[t] = lab[i0 + t];

    // per-lane bias/weight for the 8 n-tiles this lane's columns touch
    float ba1v[8], wo1v[8];
    #pragma unroll
    for (int nt = 0; nt < 8; ++nt) {
        int c = l4 + 16 * nt;
        ba1v[nt] = ba1[c];
        wo1v[nt] = wo1[c];
    }

    f32x4 acc[8];
    #pragma unroll
    for (int nt = 0; nt < 8; ++nt) acc[nt] = (f32x4){0.f, 0.f, 0.f, 0.f};

    for (int k0 = 0; k0 < D_EMB; k0 += KC) {
        // stage A chunk: 64 rows x 64 k, fp32 -> bf16 (4 float4 per thread)
        #pragma unroll
        for (int r = 0; r < 4; ++r) {
            int idx = t + 256 * r;
            int row = idx >> 4;
            int c4  = (idx & 15) * 4;
            float4 v = *reinterpret_cast<const float4*>(
                &emb[(i0 + row) * D_EMB + k0 + c4]);
            u16x4 b = { f2b(v.x), f2b(v.y), f2b(v.z), f2b(v.w) };
            *reinterpret_cast<u16x4*>(&Ash[row * LDA + c4]) = b;
        }
        // stage B chunk: 128 cols x 64 k, already bf16 (4 x 16B per thread)
        #pragma unroll
        for (int r = 0; r < 4; ++r) {
            int idx = t + 256 * r;
            int row = idx >> 3;
            int c8  = (idx & 7) * 8;
            bf16x8 vv = *reinterpret_cast<const bf16x8*>(
                &Wt[(size_t)row * D_EMB + k0 + c8]);
            *reinterpret_cast<bf16x8*>(&Bsh[row * LDA + c8]) = vv;
        }
        __syncthreads();
        #pragma unroll
        for (int ks = 0; ks < 2; ++ks) {
            bf16x8 af = *reinterpret_cast<const bf16x8*>(
                &Ash[(16 * w + l4) * LDA + 32 * ks + h4 * 8]);
            #pragma unroll
            for (int nt = 0; nt < 8; ++nt) {
                bf16x8 bfr = *reinterpret_cast<const bf16x8*>(
                    &Bsh[(l4 + 16 * nt) * LDA + 32 * ks + h4 * 8]);
                acc[nt] = __builtin_amdgcn_mfma_f32_16x16x32_bf16(
                    af, bfr, acc[nt], 0, 0, 0);
            }
        }
        __syncthreads();
    }

    // epilogue: att_pre[i] = sum_j tanh(C[i][j] + ba1[j]) * wo1[j]
    // C layout: col = l&15 (+16*nt), row = (l>>4)*4 + reg (+16*w)
    #pragma unroll
    for (int reg = 0; reg < 4; ++reg) {
        float p = 0.f;
        #pragma unroll
        for (int nt = 0; nt < 8; ++nt)
            p += tanhf(acc[nt][reg] + ba1v[nt]) * wo1v[nt];
        p += __shfl_xor(p, 1);
        p += __shfl_xor(p, 2);
        p += __shfl_xor(p, 4);
        p += __shfl_xor(p, 8);
        if (l4 == 0) att[16 * w + 4 * h4 + reg] = p;
    }
    __syncthreads();
    if (t < TILE_I) {
        float a  = att[t] + bo1[0];
        float sg = 1.f / (1.f + __expf(-a));   // in (0,1): exp needs no max-sub
        sval[t]  = __expf(sg);
    }
    __syncthreads();
    if (t < TILE_I) {                          // wave 0
        float z = sval[t];
        #pragma unroll
        for (int m = 1; m < 64; m <<= 1) z += __shfl_xor(z, m);
        if (t == 0) atomicAdd(Z1, z);
    }

    // segmented weighted accumulate: thread t owns dims 2t, 2t+1.
    // emb re-read is L2/L3-hot (round-1 FETCH == one HBM pass confirms).
    int cur = labs[0];
    float a0 = 0.f, a1 = 0.f;
    const float* ebase = emb + i0 * D_EMB + 2 * t;
    for (int ii = 0; ii < TILE_I; ++ii) {
        int b = labs[ii];
        if (b != cur) {
            atomicAdd(&raw[cur * D_EMB + 2 * t], a0);
            atomicAdd(&raw[cur * D_EMB + 2 * t + 1], a1);
            a0 = 0.f; a1 = 0.f; cur = b;
        }
        float s = sval[ii];
        float2 e = *reinterpret_cast<const float2*>(ebase + (size_t)ii * D_EMB);
        a0 = fmaf(s, e.x, a0);
        a1 = fmaf(s, e.y, a1);
    }
    atomicAdd(&raw[cur * D_EMB + 2 * t], a0);
    atomicAdd(&raw[cur * D_EMB + 2 * t + 1], a1);
}

// ============ K2: normalize bag embeddings + bag-level attention ============
__global__ __launch_bounds__(128) void k_att2(
    const float* __restrict__ Wa2, const float* __restrict__ ba2,
    const float* __restrict__ wo2, const float* __restrict__ bo2,
    float* __restrict__ raw, const float* __restrict__ Z1,
    float* __restrict__ e2, float* __restrict__ Z2)
{
    __shared__ float sec[D_EMB];
    __shared__ float hh[2];
    const int b = blockIdx.x;
    const int t = threadIdx.x;
    const float zinv = 1.f / Z1[0];
    for (int d = t; d < D_EMB; d += 128) {
        float v = raw[b * D_EMB + d] * zinv;
        raw[b * D_EMB + d] = v;            // normalized in place
        sec[d] = v;
    }
    __syncthreads();
    float dot = 0.f;
    #pragma unroll 8
    for (int d = 0; d < D_EMB; ++d) dot = fmaf(sec[d], Wa2[d * ATT + t], dot);
    float h = tanhf(dot + ba2[t]) * wo2[t];
    #pragma unroll
    for (int m = 1; m < 64; m <<= 1) h += __shfl_xor(h, m);
    if ((t & 63) == 0) hh[t >> 6] = h;
    __syncthreads();
    if (t == 0) {
        float a  = hh[0] + hh[1] + bo2[0];
        float sg = 1.f / (1.f + __expf(-a));
        float e  = __expf(sg);
        e2[b] = e;
        atomicAdd(Z2, e);
    }
}

// ============ Kv: v = W_c @ w_out ============
__global__ __launch_bounds__(256) void k_v(
    const float* __restrict__ Wc, const float* __restrict__ wout,
    float* __restrict__ v)
{
    const int t   = threadIdx.x;
    const int row = blockIdx.x * 8 + (t >> 5);
    const int l   = t & 31;
    float s = 0.f;
    #pragma unroll 4
    for (int c = l; c < 512; c += 32) s = fmaf(Wc[(size_t)row * 512 + c], wout[c], s);
    #pragma unroll
    for (int m = 1; m < 32; m <<= 1) s += __shfl_xor(s, m);
    if (l == 0) v[row] = s;
}

// ============ pool: outer_raw = sum_b e2[b] * raw[b][:] (8 blocks) ============
__global__ __launch_bounds__(256) void k_pool(
    const float* __restrict__ raw, const float* __restrict__ e2,
    float* __restrict__ outer)
{
    const int t  = threadIdx.x;
    const int b0 = blockIdx.x * 32;
    float o0 = 0.f, o1 = 0.f;
    for (int b = b0; b < b0 + 32; ++b) {
        float wgt = e2[b];
        float2 r = *reinterpret_cast<const float2*>(&raw[b * D_EMB + 2 * t]);
        o0 = fmaf(wgt, r.x, o0);
        o1 = fmaf(wgt, r.y, o1);
    }
    atomicAdd(&outer[2 * t], o0);
    atomicAdd(&outer[2 * t + 1], o1);
}

// ============ classifier: pred = sigmoid(outer/Z2 . v + bc . wout + bout) ====
__global__ __launch_bounds__(256) void k_cls(
    const float* __restrict__ outer, const float* __restrict__ Z2,
    const float* __restrict__ v, const float* __restrict__ bc,
    const float* __restrict__ wout, const float* __restrict__ bout,
    float* __restrict__ out)
{
    __shared__ float pp[4];
    const int t = threadIdx.x;
    const float z2inv = 1.f / Z2[0];
    float p = (outer[2 * t] * v[2 * t] + outer[2 * t + 1] * v[2 * t + 1]) * z2inv
            + bc[2 * t] * wout[2 * t] + bc[2 * t + 1] * wout[2 * t + 1];
    #pragma unroll
    for (int m = 1; m < 64; m <<= 1) p += __shfl_xor(p, m);
    if ((t & 63) == 0) pp[t >> 6] = p;
    __syncthreads();
    if (t == 0) {
        float s = pp[0] + pp[1] + pp[2] + pp[3] + bout[0];
        out[0] = 1.f / (1.f + __expf(-s));
    }
}

extern "C" void kernel_launch(void* const* d_in, const int* in_sizes, int n_in,
                              void* d_out, int out_size, void* d_ws, size_t ws_size,
                              hipStream_t stream)
{
    const float* emb  = (const float*)d_in[0];
    const int*   lab  = (const int*)d_in[1];
    const float* Wa1  = (const float*)d_in[2];
    const float* ba1  = (const float*)d_in[3];
    const float* wo1  = (const float*)d_in[4];
    const float* bo1  = (const float*)d_in[5];
    const float* Wa2  = (const float*)d_in[6];
    const float* ba2  = (const float*)d_in[7];
    const float* wo2  = (const float*)d_in[8];
    const float* bo2  = (const float*)d_in[9];
    const float* Wc   = (const float*)d_in[10];
    const float* bc   = (const float*)d_in[11];
    const float* wout = (const float*)d_in[12];
    const float* bout = (const float*)d_in[13];

    float* ws    = (float*)d_ws;
    float* Z1    = ws + 0;
    float* Z2    = ws + 1;
    float* v     = ws + 16;
    float* e2    = ws + 1024;
    float* outer = ws + 1536;
    float* raw   = ws + 2048;
    unsigned short* Wt = (unsigned short*)(ws + 133120);

    // zero Z1/Z2/e2/outer/raw each call (harness does not re-poison)
    hipMemsetAsync(d_ws, 0, (size_t)(2048 + NBAGS * D_EMB) * sizeof(float), stream);

    hipLaunchKernelGGL(k_prep_wt, dim3(ATT),            dim3(256), 0, stream, Wa1, Wt);
    hipLaunchKernelGGL(k_v,       dim3(64),             dim3(256), 0, stream, Wc, wout, v);
    hipLaunchKernelGGL(k_att1,    dim3(N_INST / TILE_I), dim3(256), 0, stream,
                       emb, lab, Wt, ba1, wo1, bo1, raw, Z1);
    hipLaunchKernelGGL(k_att2,    dim3(NBAGS),          dim3(128), 0, stream,
                       Wa2, ba2, wo2, bo2, raw, Z1, e2, Z2);
    hipLaunchKernelGGL(k_pool,    dim3(8),              dim3(256), 0, stream,
                       raw, e2, outer);
    hipLaunchKernelGGL(k_cls,     dim3(1),              dim3(256), 0, stream,
                       outer, Z2, v, bc, wout, bout, (float*)d_out);
}

// Round 3
// 179.161 us; speedup vs baseline: 1.7453x; 1.1002x over previous
//
#include <hip/hip_runtime.h>
#include <cstdint>
#include <cstddef>

#define N_INST 131072
#define D_EMB  512
#define ATT    128
#define NBAGS  256
#define TILE_I 128
#define KC     64
#define LDA    72   // padded LDS row stride (144 B): b128 frag reads land balanced on banks

typedef __attribute__((ext_vector_type(8))) short  bf16x8;
typedef __attribute__((ext_vector_type(4))) float  f32x4;
typedef __attribute__((ext_vector_type(4))) unsigned short u16x4;

// ---------------- workspace layout (floats) ----------------
// [0] Z1, [1] Z2
// [16..528)      v[512]       = W_c @ w_out (folded classifier)
// [1024..1280)   e2[256]      = exp(att2) per bag
// [1536..2048)   outer[512]   = unnormalized softmax-pooled bag embedding
// [2048..133120) raw[256][512]
// [133120..165888) Wt bf16 [128][512]  (W_a1 transposed, n-major)

__device__ inline unsigned short f2b(float f) {
    unsigned u = __builtin_bit_cast(unsigned, f);
    u += 0x7FFFu + ((u >> 16) & 1u);          // RNE
    return (unsigned short)(u >> 16);
}

// ============ prep: Wt[n][k] = bf16(W_a1[k][n]) ============
__global__ __launch_bounds__(256) void k_prep_wt(
    const float* __restrict__ Wa1, unsigned short* __restrict__ Wt)
{
    const int n = blockIdx.x;
    for (int k = threadIdx.x; k < D_EMB; k += 256)
        Wt[(size_t)n * D_EMB + k] = f2b(Wa1[(size_t)k * ATT + n]);
}

// ============ K1: MFMA instance attention + weighted segment sum ============
// 128 instances/block, 8 waves; wave w owns rows 16w..16w+15 x all 128 cols.
// Double-buffered KC=64 chunks, ONE barrier per chunk.
__global__ __launch_bounds__(512) void k_att1(
    const float* __restrict__ emb, const int* __restrict__ lab,
    const unsigned short* __restrict__ Wt, const float* __restrict__ ba1,
    const float* __restrict__ wo1, const float* __restrict__ bo1,
    float* __restrict__ raw, float* __restrict__ Z1)
{
    __shared__ unsigned short Ash[2][TILE_I * LDA];
    __shared__ unsigned short Bsh[2][ATT * LDA];
    __shared__ float att[TILE_I];
    __shared__ float sval[TILE_I];
    __shared__ int   labs[TILE_I];

    const int t  = threadIdx.x;
    const int w  = t >> 6;        // 0..7
    const int l  = t & 63;
    const int l4 = l & 15;
    const int h4 = l >> 4;        // 0..3
    const size_t i0 = (size_t)blockIdx.x * TILE_I;

    if (t < TILE_I) labs[t] = lab[i0 + t];

    float ba1v[8], wo1v[8];
    #pragma unroll
    for (int nt = 0; nt < 8; ++nt) {
        int c = l4 + 16 * nt;
        ba1v[nt] = ba1[c];
        wo1v[nt] = wo1[c];
    }

    f32x4 acc[8];
    #pragma unroll
    for (int nt = 0; nt < 8; ++nt) acc[nt] = (f32x4){0.f, 0.f, 0.f, 0.f};

    // ---- staging macro bodies ----
    auto stage = [&](int buf, int k0) {
        // A chunk: 128 rows x 64 k fp32 -> bf16. 2048 float4 / 512 thr = 4 each.
        #pragma unroll
        for (int r = 0; r < 4; ++r) {
            int idx = t + 512 * r;
            int row = idx >> 4;
            int c4  = (idx & 15) * 4;
            float4 v = *reinterpret_cast<const float4*>(
                &emb[(i0 + row) * D_EMB + k0 + c4]);
            u16x4 b = { f2b(v.x), f2b(v.y), f2b(v.z), f2b(v.w) };
            *reinterpret_cast<u16x4*>(&Ash[buf][row * LDA + c4]) = b;
        }
        // B chunk: 128 n x 64 k bf16. 1024 bf16x8 / 512 thr = 2 each.
        #pragma unroll
        for (int r = 0; r < 2; ++r) {
            int idx = t + 512 * r;
            int row = idx >> 3;
            int c8  = (idx & 7) * 8;
            bf16x8 vv = *reinterpret_cast<const bf16x8*>(
                &Wt[(size_t)row * D_EMB + k0 + c8]);
            *reinterpret_cast<bf16x8*>(&Bsh[buf][row * LDA + c8]) = vv;
        }
    };

    stage(0, 0);
    __syncthreads();

    int cur = 0;
    for (int c = 0; c < D_EMB / KC; ++c) {
        if (c + 1 < D_EMB / KC) stage(cur ^ 1, (c + 1) * KC);
        #pragma unroll
        for (int ks = 0; ks < 2; ++ks) {
            bf16x8 af = *reinterpret_cast<const bf16x8*>(
                &Ash[cur][(16 * w + l4) * LDA + 32 * ks + h4 * 8]);
            #pragma unroll
            for (int nt = 0; nt < 8; ++nt) {
                bf16x8 bfr = *reinterpret_cast<const bf16x8*>(
                    &Bsh[cur][(l4 + 16 * nt) * LDA + 32 * ks + h4 * 8]);
                acc[nt] = __builtin_amdgcn_mfma_f32_16x16x32_bf16(
                    af, bfr, acc[nt], 0, 0, 0);
            }
        }
        __syncthreads();   // writes to cur^1 done; reads of cur done
        cur ^= 1;
    }

    // epilogue: att_pre[i] = sum_j tanh(C[i][j] + ba1[j]) * wo1[j]
    // C layout: col = l4 + 16nt, row = 16w + 4h4 + reg   (validated round 2)
    #pragma unroll
    for (int reg = 0; reg < 4; ++reg) {
        float p = 0.f;
        #pragma unroll
        for (int nt = 0; nt < 8; ++nt)
            p += tanhf(acc[nt][reg] + ba1v[nt]) * wo1v[nt];
        p += __shfl_xor(p, 1);
        p += __shfl_xor(p, 2);
        p += __shfl_xor(p, 4);
        p += __shfl_xor(p, 8);
        if (l4 == 0) att[16 * w + 4 * h4 + reg] = p;
    }
    __syncthreads();
    if (t < TILE_I) {
        float a  = att[t] + bo1[0];
        float sg = 1.f / (1.f + __expf(-a));   // in (0,1): exp needs no max-sub
        sval[t]  = __expf(sg);
    }
    __syncthreads();
    if (t < TILE_I) {                          // waves 0 and 1
        float z = sval[t];
        #pragma unroll
        for (int m = 1; m < 64; m <<= 1) z += __shfl_xor(z, m);
        if (l == 0) atomicAdd(Z1, z);
    }

    // ---- phase 2: segmented weighted sum. thread t owns dim t (512 = D_EMB).
    // Labels sorted -> few segments; wave-uniform outer loop, branch-free inner.
    int s0 = 0;
    while (s0 < TILE_I) {
        int bag = labs[s0];
        int s1 = s0 + 1;
        while (s1 < TILE_I && labs[s1] == bag) ++s1;
        float a = 0.f;
        const float* ebase = emb + (i0 + s0) * D_EMB + t;
        int len = s1 - s0;
        #pragma unroll 4
        for (int ii = 0; ii < len; ++ii)
            a = fmaf(sval[s0 + ii], ebase[(size_t)ii * D_EMB], a);
        atomicAdd(&raw[bag * D_EMB + t], a);
        s0 = s1;
    }
}

// ============ K2: normalize bag embeddings + bag-level attention ============
__global__ __launch_bounds__(128) void k_att2(
    const float* __restrict__ Wa2, const float* __restrict__ ba2,
    const float* __restrict__ wo2, const float* __restrict__ bo2,
    float* __restrict__ raw, const float* __restrict__ Z1,
    float* __restrict__ e2, float* __restrict__ Z2)
{
    __shared__ float sec[D_EMB];
    __shared__ float hh[2];
    const int b = blockIdx.x;
    const int t = threadIdx.x;
    const float zinv = 1.f / Z1[0];
    for (int d = t; d < D_EMB; d += 128) {
        float v = raw[b * D_EMB + d] * zinv;
        raw[b * D_EMB + d] = v;            // normalized in place
        sec[d] = v;
    }
    __syncthreads();
    float dot = 0.f;
    #pragma unroll 8
    for (int d = 0; d < D_EMB; ++d) dot = fmaf(sec[d], Wa2[d * ATT + t], dot);
    float h = tanhf(dot + ba2[t]) * wo2[t];
    #pragma unroll
    for (int m = 1; m < 64; m <<= 1) h += __shfl_xor(h, m);
    if ((t & 63) == 0) hh[t >> 6] = h;
    __syncthreads();
    if (t == 0) {
        float a  = hh[0] + hh[1] + bo2[0];
        float sg = 1.f / (1.f + __expf(-a));
        float e  = __expf(sg);
        e2[b] = e;
        atomicAdd(Z2, e);
    }
}

// ============ Kv: v = W_c @ w_out ============
__global__ __launch_bounds__(256) void k_v(
    const float* __restrict__ Wc, const float* __restrict__ wout,
    float* __restrict__ v)
{
    const int t   = threadIdx.x;
    const int row = blockIdx.x * 8 + (t >> 5);
    const int l   = t & 31;
    float s = 0.f;
    #pragma unroll 4
    for (int c = l; c < 512; c += 32) s = fmaf(Wc[(size_t)row * 512 + c], wout[c], s);
    #pragma unroll
    for (int m = 1; m < 32; m <<= 1) s += __shfl_xor(s, m);
    if (l == 0) v[row] = s;
}

// ============ pool: outer_raw = sum_b e2[b] * raw[b][:] (8 blocks) ============
__global__ __launch_bounds__(256) void k_pool(
    const float* __restrict__ raw, const float* __restrict__ e2,
    float* __restrict__ outer)
{
    const int t  = threadIdx.x;
    const int b0 = blockIdx.x * 32;
    float o0 = 0.f, o1 = 0.f;
    for (int b = b0; b < b0 + 32; ++b) {
        float wgt = e2[b];
        float2 r = *reinterpret_cast<const float2*>(&raw[b * D_EMB + 2 * t]);
        o0 = fmaf(wgt, r.x, o0);
        o1 = fmaf(wgt, r.y, o1);
    }
    atomicAdd(&outer[2 * t], o0);
    atomicAdd(&outer[2 * t + 1], o1);
}

// ============ classifier: pred = sigmoid(outer/Z2 . v + bc . wout + bout) ====
__global__ __launch_bounds__(256) void k_cls(
    const float* __restrict__ outer, const float* __restrict__ Z2,
    const float* __restrict__ v, const float* __restrict__ bc,
    const float* __restrict__ wout, const float* __restrict__ bout,
    float* __restrict__ out)
{
    __shared__ float pp[4];
    const int t = threadIdx.x;
    const float z2inv = 1.f / Z2[0];
    float p = (outer[2 * t] * v[2 * t] + outer[2 * t + 1] * v[2 * t + 1]) * z2inv
            + bc[2 * t] * wout[2 * t] + bc[2 * t + 1] * wout[2 * t + 1];
    #pragma unroll
    for (int m = 1; m < 64; m <<= 1) p += __shfl_xor(p, m);
    if ((t & 63) == 0) pp[t >> 6] = p;
    __syncthreads();
    if (t == 0) {
        float s = pp[0] + pp[1] + pp[2] + pp[3] + bout[0];
        out[0] = 1.f / (1.f + __expf(-s));
    }
}

extern "C" void kernel_launch(void* const* d_in, const int* in_sizes, int n_in,
                              void* d_out, int out_size, void* d_ws, size_t ws_size,
                              hipStream_t stream)
{
    const float* emb  = (const float*)d_in[0];
    const int*   lab  = (const int*)d_in[1];
    const float* Wa1  = (const float*)d_in[2];
    const float* ba1  = (const float*)d_in[3];
    const float* wo1  = (const float*)d_in[4];
    const float* bo1  = (const float*)d_in[5];
    const float* Wa2  = (const float*)d_in[6];
    const float* ba2  = (const float*)d_in[7];
    const float* wo2  = (const float*)d_in[8];
    const float* bo2  = (const float*)d_in[9];
    const float* Wc   = (const float*)d_in[10];
    const float* bc   = (const float*)d_in[11];
    const float* wout = (const float*)d_in[12];
    const float* bout = (const float*)d_in[13];

    float* ws    = (float*)d_ws;
    float* Z1    = ws + 0;
    float* Z2    = ws + 1;
    float* v     = ws + 16;
    float* e2    = ws + 1024;
    float* outer = ws + 1536;
    float* raw   = ws + 2048;
    unsigned short* Wt = (unsigned short*)(ws + 133120);

    // zero Z1/Z2/e2/outer/raw each call (harness does not re-poison)
    hipMemsetAsync(d_ws, 0, (size_t)(2048 + NBAGS * D_EMB) * sizeof(float), stream);

    hipLaunchKernelGGL(k_prep_wt, dim3(ATT),             dim3(256), 0, stream, Wa1, Wt);
    hipLaunchKernelGGL(k_v,       dim3(64),              dim3(256), 0, stream, Wc, wout, v);
    hipLaunchKernelGGL(k_att1,    dim3(N_INST / TILE_I), dim3(512), 0, stream,
                       emb, lab, Wt, ba1, wo1, bo1, raw, Z1);
    hipLaunchKernelGGL(k_att2,    dim3(NBAGS),           dim3(128), 0, stream,
                       Wa2, ba2, wo2, bo2, raw, Z1, e2, Z2);
    hipLaunchKernelGGL(k_pool,    dim3(8),               dim3(256), 0, stream,
                       raw, e2, outer);
    hipLaunchKernelGGL(k_cls,     dim3(1),               dim3(256), 0, stream,
                       outer, Z2, v, bc, wout, bout, (float*)d_out);
}

// Round 4
// 140.274 us; speedup vs baseline: 2.2291x; 1.2772x over previous
//
#include <hip/hip_runtime.h>
#include <cstdint>
#include <cstddef>

#define N_INST 131072
#define D_EMB  512
#define ATT    128
#define NBAGS  256
#define TILE_I 64
#define LDA    520  // padded bf16 row stride (1040 B): frag reads land 2-way (free)

typedef __attribute__((ext_vector_type(8))) short  bf16x8;
typedef __attribute__((ext_vector_type(4))) float  f32x4;
typedef __attribute__((ext_vector_type(4))) unsigned short u16x4;

// ---------------- workspace layout (floats) ----------------
// [0] Z1, [1] Z2
// [16..528)      v[512]       = W_c @ w_out (folded classifier)
// [1024..1280)   e2[256]      = exp(att2) per bag
// [1536..2048)   outer[512]   = unnormalized softmax-pooled bag embedding
// [2048..133120) raw[256][512]
// [133120..165888) Wt bf16 [128][512]  (W_a1 transposed, n-major)

__device__ inline unsigned short f2b(float f) {
    unsigned u = __builtin_bit_cast(unsigned, f);
    u += 0x7FFFu + ((u >> 16) & 1u);          // RNE
    return (unsigned short)(u >> 16);
}

// ============ prep: Wt[n][k] = bf16(W_a1[k][n]) ============
__global__ __launch_bounds__(256) void k_prep_wt(
    const float* __restrict__ Wa1, unsigned short* __restrict__ Wt)
{
    const int n = blockIdx.x;
    for (int k = threadIdx.x; k < D_EMB; k += 256)
        Wt[(size_t)n * D_EMB + k] = f2b(Wa1[(size_t)k * ATT + n]);
}

// ============ K1: single-barrier MFMA attention + LDS-resident phase 2 =======
// 64 instances/block, 4 waves. Wave w owns n-cols [32w, 32w+32) (2 n-tiles),
// all 64 rows. A [64x512] bf16 lives in LDS for the whole kernel; B fragments
// live in registers (loaded from L2-hot Wt). emb is read from HBM exactly once.
__global__ __launch_bounds__(256, 2) void k_att1(
    const float* __restrict__ emb, const int* __restrict__ lab,
    const unsigned short* __restrict__ Wt, const float* __restrict__ ba1,
    const float* __restrict__ wo1, const float* __restrict__ bo1,
    float* __restrict__ raw, float* __restrict__ Z1)
{
    __shared__ unsigned short Ash[TILE_I * LDA];   // 66560 B
    __shared__ float att[TILE_I];
    __shared__ float sval[TILE_I];
    __shared__ int   labs[TILE_I];

    const int t  = threadIdx.x;
    const int w  = t >> 6;        // 0..3
    const int l  = t & 63;
    const int l4 = l & 15;
    const int h4 = l >> 4;        // 0..3
    const size_t i0 = (size_t)blockIdx.x * TILE_I;

    if (t < TILE_I) { labs[t] = lab[i0 + t]; att[t] = 0.f; }

    // ---- B fragments for this wave's 2 n-tiles: 32 x bf16x8 = 128 VGPR ----
    bf16x8 bfrag[2][16];
    #pragma unroll
    for (int nt = 0; nt < 2; ++nt) {
        const int n = 16 * (2 * w + nt) + l4;
        #pragma unroll
        for (int ks = 0; ks < 16; ++ks)
            bfrag[nt][ks] = *reinterpret_cast<const bf16x8*>(
                &Wt[(size_t)n * D_EMB + 32 * ks + 8 * h4]);
    }

    // per-lane bias/weight for this wave's columns
    float ba1v[2], wo1v[2];
    #pragma unroll
    for (int nt = 0; nt < 2; ++nt) {
        int c = 16 * (2 * w + nt) + l4;
        ba1v[nt] = ba1[c];
        wo1v[nt] = wo1[c];
    }

    // ---- stage ALL of A: 64 rows x 512 k fp32 -> bf16 LDS, 8-deep MLP ----
    #pragma unroll
    for (int g = 0; g < 4; ++g) {
        float4 v[8];
        #pragma unroll
        for (int j = 0; j < 8; ++j) {
            int idx = (g * 8 + j) * 256 + t;     // float4 index in [0, 8192)
            int row = idx >> 7;                  // 128 float4 per row
            int c4  = (idx & 127) * 4;
            v[j] = *reinterpret_cast<const float4*>(&emb[(i0 + row) * D_EMB + c4]);
        }
        #pragma unroll
        for (int j = 0; j < 8; ++j) {
            int idx = (g * 8 + j) * 256 + t;
            int row = idx >> 7;
            int c4  = (idx & 127) * 4;
            u16x4 b = { f2b(v[j].x), f2b(v[j].y), f2b(v[j].z), f2b(v[j].w) };
            *reinterpret_cast<u16x4*>(&Ash[row * LDA + c4]) = b;
        }
    }
    __syncthreads();   // the ONLY staging barrier

    // ---- score GEMM: 64 ds_read_b128 + 128 MFMA per wave ----
    f32x4 acc[4][2];
    #pragma unroll
    for (int rt = 0; rt < 4; ++rt) {
        acc[rt][0] = (f32x4){0.f, 0.f, 0.f, 0.f};
        acc[rt][1] = (f32x4){0.f, 0.f, 0.f, 0.f};
    }
    #pragma unroll
    for (int rt = 0; rt < 4; ++rt) {
        #pragma unroll
        for (int ks = 0; ks < 16; ++ks) {
            bf16x8 af = *reinterpret_cast<const bf16x8*>(
                &Ash[(16 * rt + l4) * LDA + 32 * ks + 8 * h4]);
            acc[rt][0] = __builtin_amdgcn_mfma_f32_16x16x32_bf16(
                af, bfrag[0][ks], acc[rt][0], 0, 0, 0);
            acc[rt][1] = __builtin_amdgcn_mfma_f32_16x16x32_bf16(
                af, bfrag[1][ks], acc[rt][1], 0, 0, 0);
        }
    }

    // ---- epilogue: partial scores, reduce over 16 lanes, LDS-atomic merge ----
    // C layout: col = l4 + 16*(2w+nt), row = 16rt + 4h4 + reg (validated r2)
    #pragma unroll
    for (int rt = 0; rt < 4; ++rt) {
        #pragma unroll
        for (int reg = 0; reg < 4; ++reg) {
            float p = tanhf(acc[rt][0][reg] + ba1v[0]) * wo1v[0]
                    + tanhf(acc[rt][1][reg] + ba1v[1]) * wo1v[1];
            p += __shfl_xor(p, 1);
            p += __shfl_xor(p, 2);
            p += __shfl_xor(p, 4);
            p += __shfl_xor(p, 8);
            if (l4 == 0) atomicAdd(&att[16 * rt + 4 * h4 + reg], p);
        }
    }
    __syncthreads();
    if (t < TILE_I) {
        float a  = att[t] + bo1[0];
        float sg = 1.f / (1.f + __expf(-a));   // in (0,1): exp needs no max-sub
        sval[t]  = __expf(sg);
    }
    __syncthreads();
    if (t < TILE_I) {                          // wave 0
        float z = sval[t];
        #pragma unroll
        for (int m = 1; m < 64; m <<= 1) z += __shfl_xor(z, m);
        if (t == 0) atomicAdd(Z1, z);
    }

    // ---- phase 2: weighted segment sum from LDS (bf16 -> f32 unpack) ----
    // thread t owns dims {2t, 2t+1}; ds_read_b32 per row, conflict-free.
    int s0 = 0;
    while (s0 < TILE_I) {
        int bag = labs[s0];
        int s1 = s0 + 1;
        while (s1 < TILE_I && labs[s1] == bag) ++s1;
        float a0 = 0.f, a1 = 0.f;
        #pragma unroll 8
        for (int ii = s0; ii < s1; ++ii) {
            unsigned u = *reinterpret_cast<const unsigned*>(
                &Ash[(size_t)ii * LDA + 2 * t]);
            float lo = __builtin_bit_cast(float, u << 16);
            float hi = __builtin_bit_cast(float, u & 0xffff0000u);
            float s  = sval[ii];
            a0 = fmaf(s, lo, a0);
            a1 = fmaf(s, hi, a1);
        }
        atomicAdd(&raw[bag * D_EMB + 2 * t], a0);
        atomicAdd(&raw[bag * D_EMB + 2 * t + 1], a1);
        s0 = s1;
    }
}

// ============ K2: normalize bag embeddings + bag-level attention ============
__global__ __launch_bounds__(128) void k_att2(
    const float* __restrict__ Wa2, const float* __restrict__ ba2,
    const float* __restrict__ wo2, const float* __restrict__ bo2,
    float* __restrict__ raw, const float* __restrict__ Z1,
    float* __restrict__ e2, float* __restrict__ Z2)
{
    __shared__ float sec[D_EMB];
    __shared__ float hh[2];
    const int b = blockIdx.x;
    const int t = threadIdx.x;
    const float zinv = 1.f / Z1[0];
    for (int d = t; d < D_EMB; d += 128) {
        float v = raw[b * D_EMB + d] * zinv;
        raw[b * D_EMB + d] = v;            // normalized in place
        sec[d] = v;
    }
    __syncthreads();
    float dot = 0.f;
    #pragma unroll 8
    for (int d = 0; d < D_EMB; ++d) dot = fmaf(sec[d], Wa2[d * ATT + t], dot);
    float h = tanhf(dot + ba2[t]) * wo2[t];
    #pragma unroll
    for (int m = 1; m < 64; m <<= 1) h += __shfl_xor(h, m);
    if ((t & 63) == 0) hh[t >> 6] = h;
    __syncthreads();
    if (t == 0) {
        float a  = hh[0] + hh[1] + bo2[0];
        float sg = 1.f / (1.f + __expf(-a));
        float e  = __expf(sg);
        e2[b] = e;
        atomicAdd(Z2, e);
    }
}

// ============ Kv: v = W_c @ w_out ============
__global__ __launch_bounds__(256) void k_v(
    const float* __restrict__ Wc, const float* __restrict__ wout,
    float* __restrict__ v)
{
    const int t   = threadIdx.x;
    const int row = blockIdx.x * 8 + (t >> 5);
    const int l   = t & 31;
    float s = 0.f;
    #pragma unroll 4
    for (int c = l; c < 512; c += 32) s = fmaf(Wc[(size_t)row * 512 + c], wout[c], s);
    #pragma unroll
    for (int m = 1; m < 32; m <<= 1) s += __shfl_xor(s, m);
    if (l == 0) v[row] = s;
}

// ============ pool: outer_raw = sum_b e2[b] * raw[b][:] (8 blocks) ============
__global__ __launch_bounds__(256) void k_pool(
    const float* __restrict__ raw, const float* __restrict__ e2,
    float* __restrict__ outer)
{
    const int t  = threadIdx.x;
    const int b0 = blockIdx.x * 32;
    float o0 = 0.f, o1 = 0.f;
    for (int b = b0; b < b0 + 32; ++b) {
        float wgt = e2[b];
        float2 r = *reinterpret_cast<const float2*>(&raw[b * D_EMB + 2 * t]);
        o0 = fmaf(wgt, r.x, o0);
        o1 = fmaf(wgt, r.y, o1);
    }
    atomicAdd(&outer[2 * t], o0);
    atomicAdd(&outer[2 * t + 1], o1);
}

// ============ classifier: pred = sigmoid(outer/Z2 . v + bc . wout + bout) ====
__global__ __launch_bounds__(256) void k_cls(
    const float* __restrict__ outer, const float* __restrict__ Z2,
    const float* __restrict__ v, const float* __restrict__ bc,
    const float* __restrict__ wout, const float* __restrict__ bout,
    float* __restrict__ out)
{
    __shared__ float pp[4];
    const int t = threadIdx.x;
    const float z2inv = 1.f / Z2[0];
    float p = (outer[2 * t] * v[2 * t] + outer[2 * t + 1] * v[2 * t + 1]) * z2inv
            + bc[2 * t] * wout[2 * t] + bc[2 * t + 1] * wout[2 * t + 1];
    #pragma unroll
    for (int m = 1; m < 64; m <<= 1) p += __shfl_xor(p, m);
    if ((t & 63) == 0) pp[t >> 6] = p;
    __syncthreads();
    if (t == 0) {
        float s = pp[0] + pp[1] + pp[2] + pp[3] + bout[0];
        out[0] = 1.f / (1.f + __expf(-s));
    }
}

extern "C" void kernel_launch(void* const* d_in, const int* in_sizes, int n_in,
                              void* d_out, int out_size, void* d_ws, size_t ws_size,
                              hipStream_t stream)
{
    const float* emb  = (const float*)d_in[0];
    const int*   lab  = (const int*)d_in[1];
    const float* Wa1  = (const float*)d_in[2];
    const float* ba1  = (const float*)d_in[3];
    const float* wo1  = (const float*)d_in[4];
    const float* bo1  = (const float*)d_in[5];
    const float* Wa2  = (const float*)d_in[6];
    const float* ba2  = (const float*)d_in[7];
    const float* wo2  = (const float*)d_in[8];
    const float* bo2  = (const float*)d_in[9];
    const float* Wc   = (const float*)d_in[10];
    const float* bc   = (const float*)d_in[11];
    const float* wout = (const float*)d_in[12];
    const float* bout = (const float*)d_in[13];

    float* ws    = (float*)d_ws;
    float* Z1    = ws + 0;
    float* Z2    = ws + 1;
    float* v     = ws + 16;
    float* e2    = ws + 1024;
    float* outer = ws + 1536;
    float* raw   = ws + 2048;
    unsigned short* Wt = (unsigned short*)(ws + 133120);

    // zero Z1/Z2/e2/outer/raw each call (harness does not re-poison)
    hipMemsetAsync(d_ws, 0, (size_t)(2048 + NBAGS * D_EMB) * sizeof(float), stream);

    hipLaunchKernelGGL(k_prep_wt, dim3(ATT),             dim3(256), 0, stream, Wa1, Wt);
    hipLaunchKernelGGL(k_v,       dim3(64),              dim3(256), 0, stream, Wc, wout, v);
    hipLaunchKernelGGL(k_att1,    dim3(N_INST / TILE_I), dim3(256), 0, stream,
                       emb, lab, Wt, ba1, wo1, bo1, raw, Z1);
    hipLaunchKernelGGL(k_att2,    dim3(NBAGS),           dim3(128), 0, stream,
                       Wa2, ba2, wo2, bo2, raw, Z1, e2, Z2);
    hipLaunchKernelGGL(k_pool,    dim3(8),               dim3(256), 0, stream,
                       raw, e2, outer);
    hipLaunchKernelGGL(k_cls,     dim3(1),               dim3(256), 0, stream,
                       outer, Z2, v, bc, wout, bout, (float*)d_out);
}